// Round 1
// 1110.820 us; speedup vs baseline: 2.2345x; 2.2345x over previous
//
#include <hip/hip_runtime.h>

// WindowAttentionBlock: B=4096 windows, N=49 tokens, D=384, H=12 heads, hd=32.
// v2: latency-bound fix round.
//  - fragment-major weight tiles (1KB, lane-coalesced) instead of column-major rows
//  - 12-deep rolling register prefetch of weight fragments (distance 2 K-steps),
//    prefetch crosses barriers (barriers are lgkmcnt-only: LDS ordering suffices,
//    global loads are register-private)
//  - x A-fragments hoisted to registers once (48 VGPRs); x LDS region becomes dead
//    and O is written directly into it per head (wave-private rows) -> no opack
//  - head loop NOT unrolled (I$-resident body); per-head biases prefetched early

#define NWIN   4096
#define NTOK   49
#define DMODEL 384
#define NH     12
#define HD     32
#define XPITCH 392   // x/O row pitch in shorts (384+8)
#define QPITCH 40    // Q/K row pitch (32+8)
#define VPITCH 72    // Vt and W row pitch (64+8)
#define SCALE  2.9802322387695312e-08f   // (32)^-5, faithful to reference
#define NEGBIG -30000.0f

typedef __attribute__((ext_vector_type(8))) short short8;
typedef __attribute__((ext_vector_type(4))) short short4v;
typedef __attribute__((ext_vector_type(4))) float float4v;

__device__ __align__(16) unsigned short g_wT[4 * DMODEL * DMODEL];
__device__ int g_dt;   // 0 = bf16 tensors, 1 = fp32 tensors

__device__ __forceinline__ float b2f(unsigned short h) {
  union { unsigned u; float f; } t; t.u = ((unsigned)h) << 16; return t.f;
}
__device__ __forceinline__ unsigned short f2b(float f) {
  union { float f; unsigned u; } t; t.f = f;
  return (unsigned short)((t.u + 0x7fffu + ((t.u >> 16) & 1u)) >> 16);
}

// Dtype sniff (unchanged): bf16 -> ~2048 sane exponents, fp32 -> ~310.
__global__ void detect_dtype(const unsigned short* __restrict__ x) {
  __shared__ int cnt;
  if (threadIdx.x == 0) cnt = 0;
  __syncthreads();
  int local = 0;
  for (int i = threadIdx.x; i < 2048; i += 256) {
    unsigned short h = x[2 * i];
    int e = (h >> 7) & 0xFF;
    if (e >= 0x6A && e <= 0x90) local++;
  }
  atomicAdd(&cnt, local);
  __syncthreads();
  if (threadIdx.x == 0) g_dt = (cnt < 1024) ? 1 : 0;
}

// Fragment-major weight prep.
// QKV region [0, 442368): tile t = (h*12 + ks)*6 + (mat*2 + nt), 512 shorts/tile.
// Wp  region [442368, 589824): tile t' = (wv*12 + ks)*6 + nt.
// Within a tile, element l*8 + j (l = lane 0..63, j = 0..7) holds
//   W[k = ks*32 + (l>>4)*8 + j][colbase + (l&15)]   (bf16)
// so a wave's B-fragment load is one contiguous 1KB global_load_dwordx4.
__global__ void prep_weights(const void* __restrict__ Wq,
                             const void* __restrict__ Wk,
                             const void* __restrict__ Wv,
                             const void* __restrict__ Wp) {
  int o = blockIdx.x * 256 + threadIdx.x;      // 0 .. 589823 exactly
  int e = o & 511;
  int t = o >> 9;
  int l = e >> 3, j = e & 7;
  int c = l & 15, qd = l >> 4;
  int k, col;
  const void* W;
  if (t < 864) {                               // QKV tiles
    int h = t / 72, r = t - h * 72;
    int ks = r / 6, i = r - ks * 6;
    int mat = i >> 1, nt = i & 1;
    W = (mat == 0) ? Wq : (mat == 1) ? Wk : Wv;
    k = ks * 32 + qd * 8 + j;
    col = h * 32 + nt * 16 + c;
  } else {                                     // Wp tiles
    int tp = t - 864;
    int wv = tp / 72, r = tp - wv * 72;
    int ks = r / 6, nt = r - ks * 6;
    W = Wp;
    k = ks * 32 + qd * 8 + j;
    col = wv * 96 + nt * 16 + c;
  }
  unsigned short v;
  if (g_dt) v = f2b(((const float*)W)[k * DMODEL + col]);
  else      v = ((const unsigned short*)W)[k * DMODEL + col];
  g_wT[o] = v;
}

// Barrier with LDS-only drain: global register prefetches stay in flight.
#define BAR() do {                                          \
    asm volatile("s_waitcnt lgkmcnt(0)" ::: "memory");      \
    __builtin_amdgcn_s_barrier();                           \
    asm volatile("" ::: "memory");                          \
  } while (0)

// LDS layout (shorts):
//   [0, 19208)        x window [49][XPITCH] (bf16); becomes O after xa hoist
//   [19208, 21168)    sQ [49][QPITCH]
//   [21168, 23128)    sK [49][QPITCH]
//   [23128, 25432)    sV Vt [32][VPITCH] (token dim padded to 64, zeros >=49)
//   [25432, 28960)    sW W  [49][VPITCH] (softmax weights, wave-local rows)
__global__ __launch_bounds__(256, 2)
void win_attn(const void* __restrict__ xg_,
              const void* __restrict__ maskg_,
              const void* __restrict__ bqg_,
              const void* __restrict__ bkg_,
              const void* __restrict__ bvg_,
              const void* __restrict__ bpg_,
              void* __restrict__ outg_)
{
  __shared__ __align__(16) short lds[28960];
  const int dt   = g_dt;           // uniform across grid
  const int win  = blockIdx.x;
  const int tid  = threadIdx.x;
  const int wv   = tid >> 6;       // wave 0..3 = M-band owner
  const int lane = tid & 63;
  const int c    = lane & 15;
  const int qd   = lane >> 4;

  const unsigned short* const wlane = g_wT + lane * 8;

  // ---- earliest possible weight prefetch: head 0, ks = 0..1 (12 tiles) ----
  short8 wb[12];
  #pragma unroll
  for (int t = 0; t < 12; ++t)
    wb[t] = *(const short8*)(wlane + t * 512);

  // ---- zero-init attention scratch ----
  {
    unsigned* z = (unsigned*)&lds[19208];            // 9752 shorts = 4876 uints
    for (int i = tid; i < 4876; i += 256) z[i] = 0u;
  }

  // ---- stage x window into LDS as bf16 ----
  if (dt == 0) {
    const uint4* src = (const uint4*)((const unsigned short*)xg_ + (size_t)win * (NTOK * DMODEL));
    for (int i = tid; i < (NTOK * DMODEL) / 8; i += 256) {
      int row = i / 48, col = i - row * 48;
      *(uint4*)&lds[row * XPITCH + col * 8] = src[i];
    }
  } else {
    const float4* src = (const float4*)((const float*)xg_ + (size_t)win * (NTOK * DMODEL));
    for (int i = tid; i < (NTOK * DMODEL) / 4; i += 256) {
      int row = i / 96, colq = i - row * 96;
      float4 f = src[i];
      short4v p;
      p[0] = (short)f2b(f.x); p[1] = (short)f2b(f.y);
      p[2] = (short)f2b(f.z); p[3] = (short)f2b(f.w);
      *(short4v*)&lds[row * XPITCH + colq * 4] = p;
    }
  }

  short* const sQ = lds + 19208;
  short* const sK = lds + 21168;
  short* const sV = lds + 23128;
  short* const sW = lds + 25432;

  const int arow = (wv * 16 + c < NTOK) ? (wv * 16 + c) : (NTOK - 1);

  // ---- mask additions for this wave's 16 score rows (all heads reuse) ----
  float madd[4][4];
  #pragma unroll
  for (int r = 0; r < 4; ++r) {
    int m = wv * 16 + qd * 4 + r;
    #pragma unroll
    for (int nt = 0; nt < 4; ++nt) {
      int n = nt * 16 + c;
      float v;
      if (n < NTOK) {
        if (m < NTOK) {
          size_t off = (size_t)win * (NTOK * NTOK) + m * NTOK + n;
          v = dt ? ((const float*)maskg_)[off] : b2f(((const unsigned short*)maskg_)[off]);
        } else v = 0.f;
      } else v = NEGBIG;
      madd[r][nt] = v;
    }
  }

  BAR();   // x staged + scratch zeroed

  // ---- hoist x A-fragments once (wave reads only its own 16-row band) ----
  short8 xa[12];
  #pragma unroll
  for (int ks = 0; ks < 12; ++ks)
    xa[ks] = *(const short8*)&lds[arow * XPITCH + ks * 32 + qd * 8];

  // x region is now dead for this wave; O is written there (same wave-private
  // rows), so no barrier is needed between xa reads and O writes.
  short* const sO = lds;

  const float4v z4 = {0.f, 0.f, 0.f, 0.f};

  #pragma unroll 1   // keep body I$-resident; all reg arrays statically indexed
  for (int h = 0; h < NH; ++h) {
    const unsigned short* const wh = wlane + h * 36864;

    // per-head biases: issue loads before the MFMA loop, consume at store time
    float biasQ[2], biasK[2], biasV[2];
    #pragma unroll
    for (int nt = 0; nt < 2; ++nt) {
      const int col = h * 32 + nt * 16 + c;
      biasQ[nt] = dt ? ((const float*)bqg_)[col] : b2f(((const unsigned short*)bqg_)[col]);
      biasK[nt] = dt ? ((const float*)bkg_)[col] : b2f(((const unsigned short*)bkg_)[col]);
      biasV[nt] = dt ? ((const float*)bvg_)[col] : b2f(((const unsigned short*)bvg_)[col]);
    }

    // ---- QKV projection, rolling 12-deep prefetch (distance 2 K-steps).
    // At ks=10,11 the prefetch targets the NEXT head's ks=0,1 tiles, which
    // then fly across both barriers and the softmax phase. (For h=11 those
    // land harmlessly in the Wp region and are overwritten before use.)
    float4v aQ0 = z4, aQ1 = z4, aK0 = z4, aK1 = z4, aV0 = z4, aV1 = z4;
    #pragma unroll
    for (int ks = 0; ks < 12; ++ks) {
      const int s = (ks & 1) * 6;
      const unsigned short* pf = (ks < 10) ? (wh + ((ks + 2) * 6) * 512)
                                           : (wh + 36864 + ((ks - 10) * 6) * 512);
      aQ0 = __builtin_amdgcn_mfma_f32_16x16x32_bf16(xa[ks], wb[s + 0], aQ0, 0, 0, 0);
      wb[s + 0] = *(const short8*)(pf + 0 * 512);
      aQ1 = __builtin_amdgcn_mfma_f32_16x16x32_bf16(xa[ks], wb[s + 1], aQ1, 0, 0, 0);
      wb[s + 1] = *(const short8*)(pf + 1 * 512);
      aK0 = __builtin_amdgcn_mfma_f32_16x16x32_bf16(xa[ks], wb[s + 2], aK0, 0, 0, 0);
      wb[s + 2] = *(const short8*)(pf + 2 * 512);
      aK1 = __builtin_amdgcn_mfma_f32_16x16x32_bf16(xa[ks], wb[s + 3], aK1, 0, 0, 0);
      wb[s + 3] = *(const short8*)(pf + 3 * 512);
      aV0 = __builtin_amdgcn_mfma_f32_16x16x32_bf16(xa[ks], wb[s + 4], aV0, 0, 0, 0);
      wb[s + 4] = *(const short8*)(pf + 4 * 512);
      aV1 = __builtin_amdgcn_mfma_f32_16x16x32_bf16(xa[ks], wb[s + 5], aV1, 0, 0, 0);
      wb[s + 5] = *(const short8*)(pf + 5 * 512);
    }

    // ---- store Q,K row-major; V transposed (tokens >= 49 stay zero) ----
    #pragma unroll
    for (int nt = 0; nt < 2; ++nt) {
      const float4v q = nt ? aQ1 : aQ0;
      const float4v k = nt ? aK1 : aK0;
      const float4v v = nt ? aV1 : aV0;
      short4v vp;
      #pragma unroll
      for (int r = 0; r < 4; ++r) {
        const int m = wv * 16 + qd * 4 + r;
        if (m < NTOK) {
          sQ[m * QPITCH + nt * 16 + c] = (short)f2b(q[r] + biasQ[nt]);
          sK[m * QPITCH + nt * 16 + c] = (short)f2b(k[r] + biasK[nt]);
        }
        vp[r] = (short)((m < NTOK) ? f2b(v[r] + biasV[nt]) : (unsigned short)0);
      }
      *(short4v*)&sV[(nt * 16 + c) * VPITCH + wv * 16 + qd * 4] = vp;
    }
    BAR();   // (1) Q,K,Vt visible to all waves

    // ---- scores: S[band][64 cols], K-dim = hd = 32 = one MFMA step ----
    float4v aS[4] = {z4, z4, z4, z4};
    {
      const short8 aq = *(const short8*)&sQ[arow * QPITCH + qd * 8];
      #pragma unroll
      for (int nt = 0; nt < 4; ++nt) {
        int kr = nt * 16 + c; if (kr > NTOK - 1) kr = NTOK - 1;
        const short8 bk8 = *(const short8*)&sK[kr * QPITCH + qd * 8];
        aS[nt] = __builtin_amdgcn_mfma_f32_16x16x32_bf16(aq, bk8, aS[nt], 0, 0, 0);
      }
    }

    // ---- softmax (rows wave-local; sW region private -> no barrier) ----
    #pragma unroll
    for (int r = 0; r < 4; ++r) {
      float s0 = fmaf(aS[0][r], SCALE, madd[r][0]);
      float s1 = fmaf(aS[1][r], SCALE, madd[r][1]);
      float s2 = fmaf(aS[2][r], SCALE, madd[r][2]);
      float s3 = fmaf(aS[3][r], SCALE, madd[r][3]);
      float mx = fmaxf(fmaxf(s0, s1), fmaxf(s2, s3));
      mx = fmaxf(mx, __shfl_xor(mx, 1));
      mx = fmaxf(mx, __shfl_xor(mx, 2));
      mx = fmaxf(mx, __shfl_xor(mx, 4));
      mx = fmaxf(mx, __shfl_xor(mx, 8));
      float e0 = __expf(fminf(s0 - mx, 0.f));
      float e1 = __expf(fminf(s1 - mx, 0.f));
      float e2 = __expf(fminf(s2 - mx, 0.f));
      float e3 = __expf(fminf(s3 - mx, 0.f));
      float sum = e0 + e1 + e2 + e3;
      sum += __shfl_xor(sum, 1);
      sum += __shfl_xor(sum, 2);
      sum += __shfl_xor(sum, 4);
      sum += __shfl_xor(sum, 8);
      float inv = 1.0f / sum;
      int m = wv * 16 + qd * 4 + r;
      if (m < NTOK) {
        sW[m * VPITCH +  0 + c] = (short)f2b(e0 * inv);
        sW[m * VPITCH + 16 + c] = (short)f2b(e1 * inv);
        sW[m * VPITCH + 32 + c] = (short)f2b(e2 * inv);
        sW[m * VPITCH + 48 + c] = (short)f2b(e3 * inv);
      }
    }

    // ---- PV: O_band = W[band][64] @ Vt[64 tok][32 hd] ----
    float4v aO0 = z4, aO1 = z4;
    #pragma unroll
    for (int ks = 0; ks < 2; ++ks) {
      const short8 aw = *(const short8*)&sW[arow * VPITCH + ks * 32 + qd * 8];
      const short8 b0 = *(const short8*)&sV[(0 * 16 + c) * VPITCH + ks * 32 + qd * 8];
      const short8 b1 = *(const short8*)&sV[(1 * 16 + c) * VPITCH + ks * 32 + qd * 8];
      aO0 = __builtin_amdgcn_mfma_f32_16x16x32_bf16(aw, b0, aO0, 0, 0, 0);
      aO1 = __builtin_amdgcn_mfma_f32_16x16x32_bf16(aw, b1, aO1, 0, 0, 0);
    }

    // ---- O store: directly into dead x region (wave-private rows) ----
    #pragma unroll
    for (int r = 0; r < 4; ++r) {
      const int m = wv * 16 + qd * 4 + r;
      if (m < NTOK) {
        sO[m * XPITCH + h * 32 +  0 + c] = (short)f2b(aO0[r]);
        sO[m * XPITCH + h * 32 + 16 + c] = (short)f2b(aO1[r]);
      }
    }
    BAR();   // (2) all scratch reads done before next head overwrites
  }
  // Last BAR also makes all waves' O rows visible for the output projection.

  // ---- output projection: each wave 96 cols; out = O @ Wp + bp ----
  const unsigned short* const wp = g_wT + 442368 + wv * 36864 + lane * 8;
  #pragma unroll
  for (int t = 0; t < 12; ++t)
    wb[t] = *(const short8*)(wp + t * 512);

  float biasP[6];
  #pragma unroll
  for (int nt = 0; nt < 6; ++nt) {
    const int col = wv * 96 + nt * 16 + c;
    biasP[nt] = dt ? ((const float*)bpg_)[col] : b2f(((const unsigned short*)bpg_)[col]);
  }

  float4v aP[4][6];
  #pragma unroll
  for (int mt = 0; mt < 4; ++mt)
    #pragma unroll
    for (int nt = 0; nt < 6; ++nt) aP[mt][nt] = z4;

  short8 af[2][4];
  #pragma unroll
  for (int mt = 0; mt < 4; ++mt) {
    int row = mt * 16 + c; if (row > NTOK - 1) row = NTOK - 1;
    af[0][mt] = *(const short8*)&sO[row * XPITCH + qd * 8];
  }

  #pragma unroll
  for (int ks = 0; ks < 12; ++ks) {
    const int cs = ks & 1;
    if (ks < 11) {
      #pragma unroll
      for (int mt = 0; mt < 4; ++mt) {
        int row = mt * 16 + c; if (row > NTOK - 1) row = NTOK - 1;
        af[cs ^ 1][mt] = *(const short8*)&sO[row * XPITCH + (ks + 1) * 32 + qd * 8];
      }
    }
    const int s = cs * 6;
    #pragma unroll
    for (int nt = 0; nt < 6; ++nt) {
      aP[0][nt] = __builtin_amdgcn_mfma_f32_16x16x32_bf16(af[cs][0], wb[s + nt], aP[0][nt], 0, 0, 0);
      aP[1][nt] = __builtin_amdgcn_mfma_f32_16x16x32_bf16(af[cs][1], wb[s + nt], aP[1][nt], 0, 0, 0);
      aP[2][nt] = __builtin_amdgcn_mfma_f32_16x16x32_bf16(af[cs][2], wb[s + nt], aP[2][nt], 0, 0, 0);
      aP[3][nt] = __builtin_amdgcn_mfma_f32_16x16x32_bf16(af[cs][3], wb[s + nt], aP[3][nt], 0, 0, 0);
      if (ks < 10) wb[s + nt] = *(const short8*)(wp + ((ks + 2) * 6 + nt) * 512);
    }
  }

  #pragma unroll
  for (int nt = 0; nt < 6; ++nt) {
    const int col = wv * 96 + nt * 16 + c;
    #pragma unroll
    for (int mt = 0; mt < 4; ++mt) {
      #pragma unroll
      for (int r = 0; r < 4; ++r) {
        const int m = mt * 16 + qd * 4 + r;
        if (m < NTOK) {
          const float v = aP[mt][nt][r] + biasP[nt];
          const size_t off = (size_t)win * (NTOK * DMODEL) + m * DMODEL + col;
          if (dt) ((float*)outg_)[off] = v;
          else    ((unsigned short*)outg_)[off] = f2b(v);
        }
      }
    }
  }
}

extern "C" void kernel_launch(void* const* d_in, const int* in_sizes, int n_in,
                              void* d_out, int out_size, void* d_ws, size_t ws_size,
                              hipStream_t stream) {
  const void* x    = d_in[0];
  const void* mask = d_in[1];
  const void* Wq   = d_in[2];
  const void* bq   = d_in[3];
  const void* Wk   = d_in[4];
  const void* bk   = d_in[5];
  const void* Wv   = d_in[6];
  const void* bv   = d_in[7];
  const void* Wp   = d_in[8];
  const void* bp   = d_in[9];

  detect_dtype<<<1, 256, 0, stream>>>((const unsigned short*)x);
  prep_weights<<<(4 * DMODEL * DMODEL) / 256, 256, 0, stream>>>(Wq, Wk, Wv, Wp);
  win_attn<<<NWIN, 256, 0, stream>>>(x, mask, bq, bk, bv, bp, d_out);
}

// Round 3
// 1008.842 us; speedup vs baseline: 2.4603x; 1.1011x over previous
//
#include <hip/hip_runtime.h>

// WindowAttentionBlock: B=4096 windows, N=49 tokens, D=384, H=12 heads, hd=32.
// v3.1: 32x32x16 MFMA attention core with swapped-operand scores.
// (v3 bugfix: next-head prefetch offset is 144 tiles (head h+2), not 72 (h+1))
//  - wave = (q-band of 32 rows, head-of-pair); QKV B-tiles loaded by 2 waves
//    instead of 4 (weight traffic halved)
//  - S^T = mfma(K, Q): each lane owns a q-row's keys (split with one partner
//    lane) -> in-register softmax (2 shuffles/head), P fed to PV via
//    v_cvt_pk_bf16_f32 + shfl_xor(32); sW LDS buffer eliminated
//  - 2 barriers per head-PAIR (12+2 per window, was 24)
//  - x A-fragments in 96 VGPRs; out-projection kept as v2 (16x16, fragment-
//    major Wp tiles prefetched during the last pair's QKV tail)

#define NWIN   4096
#define NTOK   49
#define DMODEL 384
#define NH     12
#define HD     32
#define XPITCH 392   // x/O row pitch in shorts (384+8)
#define QP     40    // Q/K row pitch (32+8), 80 B, 16-aligned
#define VP     72    // Vt row pitch (64+8), 144 B, 16-aligned
#define SCALE  2.9802322387695312e-08f   // (32)^-5, faithful to reference
#define NEGBIG -30000.0f

#define S_BASE 19208          // scratch start (shorts)
#define S_STR  6224           // per-head-slot scratch size (shorts)
// per slot: sQ [49][40] @0, sK [49][40] @1960, sVt [32][72] @3920
#define LDS_TOT 31656         // 63312 B

typedef __attribute__((ext_vector_type(8)))  short short8;
typedef __attribute__((ext_vector_type(4)))  short short4v;
typedef __attribute__((ext_vector_type(4)))  float float4v;
typedef __attribute__((ext_vector_type(16))) float float16v;

__device__ __align__(16) unsigned short g_wT[4 * DMODEL * DMODEL];
__device__ int g_dt;   // 0 = bf16 tensors, 1 = fp32 tensors

__device__ __forceinline__ float b2f(unsigned short h) {
  union { unsigned u; float f; } t; t.u = ((unsigned)h) << 16; return t.f;
}
__device__ __forceinline__ unsigned short f2b(float f) {
  union { float f; unsigned u; } t; t.f = f;
  return (unsigned short)((t.u + 0x7fffu + ((t.u >> 16) & 1u)) >> 16);
}
__device__ __forceinline__ unsigned cvt_pk_bf16(float lo, float hi) {
  unsigned r;
  asm("v_cvt_pk_bf16_f32 %0, %1, %2" : "=v"(r) : "v"(lo), "v"(hi));
  return r;
}

// Dtype sniff (unchanged): bf16 -> ~2048 sane exponents, fp32 -> ~310.
__global__ void detect_dtype(const unsigned short* __restrict__ x) {
  __shared__ int cnt;
  if (threadIdx.x == 0) cnt = 0;
  __syncthreads();
  int local = 0;
  for (int i = threadIdx.x; i < 2048; i += 256) {
    unsigned short h = x[2 * i];
    int e = (h >> 7) & 0xFF;
    if (e >= 0x6A && e <= 0x90) local++;
  }
  atomicAdd(&cnt, local);
  __syncthreads();
  if (threadIdx.x == 0) g_dt = (cnt < 1024) ? 1 : 0;
}

// Weight prep.
// QKV region [0, 442368): 32x32x16 B-fragment tiles, 512 shorts each.
//   tile t = (h*24 + ks)*3 + mat; element l*8+j = W_mat[ks*16+(l>>5)*8+j][h*32+(l&31)]
// Wp region [442368, 589824): 16x16x32 tiles (v2 layout).
//   tile t' = (wv*12 + ks)*6 + nt; element l*8+j = Wp[ks*32+(l>>4)*8+j][wv*96+nt*16+(l&15)]
__global__ void prep_weights(const void* __restrict__ Wq,
                             const void* __restrict__ Wk,
                             const void* __restrict__ Wv,
                             const void* __restrict__ Wp) {
  int o = blockIdx.x * 256 + threadIdx.x;      // 0 .. 589823 exactly
  int e = o & 511;
  int t = o >> 9;
  int l = e >> 3, j = e & 7;
  int k, col;
  const void* W;
  if (t < 864) {                               // QKV tiles (32x32 frag)
    int h = t / 72, r = t - h * 72;
    int ks = r / 3, mat = r - ks * 3;
    W = (mat == 0) ? Wq : (mat == 1) ? Wk : Wv;
    k = ks * 16 + (l >> 5) * 8 + j;
    col = h * 32 + (l & 31);
  } else {                                     // Wp tiles (16x16 frag)
    int tp = t - 864;
    int wv = tp / 72, r = tp - wv * 72;
    int ks = r / 6, nt = r - ks * 6;
    W = Wp;
    k = ks * 32 + (l >> 4) * 8 + j;
    col = wv * 96 + nt * 16 + (l & 15);
  }
  unsigned short v;
  if (g_dt) v = f2b(((const float*)W)[k * DMODEL + col]);
  else      v = ((const unsigned short*)W)[k * DMODEL + col];
  g_wT[o] = v;
}

// Barrier with LDS-only drain: global register prefetches stay in flight.
#define BAR() do {                                          \
    asm volatile("s_waitcnt lgkmcnt(0)" ::: "memory");      \
    __builtin_amdgcn_s_barrier();                           \
    asm volatile("" ::: "memory");                          \
  } while (0)

#define MFMA32(A, B, C) __builtin_amdgcn_mfma_f32_32x32x16_bf16((A), (B), (C), 0, 0, 0)
#define MFMA16(A, B, C) __builtin_amdgcn_mfma_f32_16x16x32_bf16((A), (B), (C), 0, 0, 0)

__global__ __launch_bounds__(256, 2)
void win_attn(const void* __restrict__ xg_,
              const void* __restrict__ maskg_,
              const void* __restrict__ bqg_,
              const void* __restrict__ bkg_,
              const void* __restrict__ bvg_,
              const void* __restrict__ bpg_,
              void* __restrict__ outg_)
{
  __shared__ __align__(16) short lds[LDS_TOT];
  const int dt   = g_dt;
  const int win  = blockIdx.x;
  const int tid  = threadIdx.x;
  const int wv   = tid >> 6;
  const int lane = tid & 63;
  const int cl   = lane & 31;      // 32-wide col index (attn core)
  const int hi   = lane >> 5;      // half-wave
  const int c    = lane & 15;      // 16-wide col index (out-proj)
  const int qd   = lane >> 4;
  const int b    = wv & 1;         // q-band (rows b*32 .. b*32+31)
  const int h2   = wv >> 1;        // head-of-pair slot

  const unsigned short* const wl = g_wT + lane * 8;

  // ---- earliest weight prefetch: head h2, ks 0..3 (12 tiles) ----
  short8 wb[12];
  {
    const unsigned short* w0 = wl + (h2 * 72) * 512;
    #pragma unroll
    for (int t = 0; t < 12; ++t) wb[t] = *(const short8*)(w0 + t * 512);
  }

  // ---- zero-init scratch (Vt pad rows must be 0; rest for safety) ----
  {
    unsigned* z = (unsigned*)&lds[S_BASE];      // 12448 shorts = 6224 uints
    for (int i = tid; i < 6224; i += 256) z[i] = 0u;
  }

  // ---- stage x window into LDS as bf16 ----
  if (dt == 0) {
    const uint4* src = (const uint4*)((const unsigned short*)xg_ + (size_t)win * (NTOK * DMODEL));
    for (int i = tid; i < (NTOK * DMODEL) / 8; i += 256) {
      int row = i / 48, col = i - row * 48;
      *(uint4*)&lds[row * XPITCH + col * 8] = src[i];
    }
  } else {
    const float4* src = (const float4*)((const float*)xg_ + (size_t)win * (NTOK * DMODEL));
    for (int i = tid; i < (NTOK * DMODEL) / 4; i += 256) {
      int row = i / 96, colq = i - row * 96;
      float4 f = src[i];
      short4v p;
      p[0] = (short)f2b(f.x); p[1] = (short)f2b(f.y);
      p[2] = (short)f2b(f.z); p[3] = (short)f2b(f.w);
      *(short4v*)&lds[row * XPITCH + colq * 4] = p;
    }
  }

  short* const sQh = lds + S_BASE + h2 * S_STR;
  short* const sKh = sQh + 1960;
  short* const sVt = sQh + 3920;
  short* const sO  = lds;          // x region becomes O after xa hoist

  // ---- packed mask additions: lane's 32 keys for its q-row (bf16 pairs) ----
  unsigned maddpk[16];
  {
    int qrow = b * 32 + cl; if (qrow > NTOK - 1) qrow = NTOK - 1;
    const size_t mb = (size_t)win * (NTOK * NTOK) + (size_t)qrow * NTOK;
    #pragma unroll
    for (int kt = 0; kt < 2; ++kt)
      #pragma unroll
      for (int i = 0; i < 8; ++i) {
        int k0 = kt * 32 + ((2 * i) & 3) + 8 * ((2 * i) >> 2) + 4 * hi;  // even
        float m0 = (k0     < NTOK)
          ? (dt ? ((const float*)maskg_)[mb + k0]     : b2f(((const unsigned short*)maskg_)[mb + k0]))
          : NEGBIG;
        float m1 = (k0 + 1 < NTOK)
          ? (dt ? ((const float*)maskg_)[mb + k0 + 1] : b2f(((const unsigned short*)maskg_)[mb + k0 + 1]))
          : NEGBIG;
        maddpk[kt * 8 + i] = cvt_pk_bf16(m0, m1);
      }
  }

  BAR();   // x staged + scratch zeroed

  // ---- hoist x A-fragments for this wave's 32-row band (96 VGPRs) ----
  short8 xa[24];
  {
    const int xrow = b * 32 + cl;
    const int xr   = (xrow < NTOK) ? xrow : 0;
    const short8 z8 = {0, 0, 0, 0, 0, 0, 0, 0};
    #pragma unroll
    for (int ks = 0; ks < 24; ++ks) {
      short8 t = *(const short8*)&lds[xr * XPITCH + ks * 16 + hi * 8];
      xa[ks] = (xrow < NTOK) ? t : z8;
    }
  }

  const float4v z4 = {0.f, 0.f, 0.f, 0.f};

  #pragma unroll 1
  for (int p = 0; p < 6; ++p) {
    const int h = 2 * p + h2;
    const unsigned short* const wh = wl + h * 72 * 512;

    // per-head biases (issue early, consume at store)
    const int colh = h * 32 + cl;
    const float biasQ = dt ? ((const float*)bqg_)[colh] : b2f(((const unsigned short*)bqg_)[colh]);
    const float biasK = dt ? ((const float*)bkg_)[colh] : b2f(((const unsigned short*)bkg_)[colh]);
    const float biasV = dt ? ((const float*)bvg_)[colh] : b2f(((const unsigned short*)bvg_)[colh]);

    // ---- QKV: 24 K-steps of 16, rolling prefetch distance 4 ----
    float16v aQ, aK, aV;
    #pragma unroll
    for (int i = 0; i < 16; ++i) { aQ[i] = 0.f; aK[i] = 0.f; aV[i] = 0.f; }
    #pragma unroll
    for (int ks = 0; ks < 24; ++ks) {
      const int s = (ks & 3) * 3;
      const short8 a = xa[ks];
      aQ = MFMA32(a, wb[s + 0], aQ);
      aK = MFMA32(a, wb[s + 1], aK);
      aV = MFMA32(a, wb[s + 2], aV);
      const unsigned short* pf;
      if (ks < 20)      pf = wh + ((ks + 4) * 3) * 512;                    // this head
      else if (p < 5)   pf = wh + (144 + (ks - 20) * 3) * 512;             // next head (h+2)
      else              pf = g_wT + 442368 + wv * 36864 + lane * 8 + ((ks - 20) * 3) * 512; // Wp tiles 0..11
      wb[s + 0] = *(const short8*)(pf + 0 * 512);
      wb[s + 1] = *(const short8*)(pf + 1 * 512);
      wb[s + 2] = *(const short8*)(pf + 2 * 512);
    }

    // ---- store Q,K row-major [tok][hd]; V transposed [hd][tok] ----
    #pragma unroll
    for (int i = 0; i < 16; ++i) {
      const int tok = (i & 3) + 8 * (i >> 2) + 4 * hi + b * 32;
      if (tok < NTOK) {
        sQh[tok * QP + cl] = (short)f2b(aQ[i] + biasQ);
        sKh[tok * QP + cl] = (short)f2b(aK[i] + biasK);
      }
    }
    #pragma unroll
    for (int i = 0; i < 8; ++i) {
      const int tok = ((2 * i) & 3) + 8 * ((2 * i) >> 2) + 4 * hi + b * 32; // even
      if (tok < NTOK) {
        float v0 = aV[2 * i] + biasV;
        float v1 = (tok + 1 < NTOK) ? (aV[2 * i + 1] + biasV) : 0.f;
        *(unsigned*)&sVt[cl * VP + tok] = cvt_pk_bf16(v0, v1);
      }
    }
    BAR();   // (1) Q,K,Vt of both bands visible

    // ---- scores (swapped): S^T[key][q] = mfma(A=K, B=Q), K-dim = hd = 32 ----
    float16v S0, S1;
    #pragma unroll
    for (int i = 0; i < 16; ++i) { S0[i] = 0.f; S1[i] = 0.f; }
    {
      int qr  = b * 32 + cl; if (qr > NTOK - 1) qr = NTOK - 1;
      const int kr0 = cl;                                  // keys 0..31, all valid
      int kr1 = 32 + cl; if (kr1 > NTOK - 1) kr1 = NTOK - 1;
      #pragma unroll
      for (int ks = 0; ks < 2; ++ks) {
        const short8 qf  = *(const short8*)&sQh[qr  * QP + ks * 16 + hi * 8];
        const short8 kf0 = *(const short8*)&sKh[kr0 * QP + ks * 16 + hi * 8];
        const short8 kf1 = *(const short8*)&sKh[kr1 * QP + ks * 16 + hi * 8];
        S0 = MFMA32(kf0, qf, S0);
        S1 = MFMA32(kf1, qf, S1);
      }
    }

    // ---- in-register softmax over this lane's 32 keys (+1 partner lane) ----
    // lane's key (kt, reg) = kt*32 + (reg&3) + 8*(reg>>2) + 4*hi
    float w32[32];
    #pragma unroll
    for (int kt = 0; kt < 2; ++kt)
      #pragma unroll
      for (int i = 0; i < 8; ++i) {
        const unsigned pk = maddpk[kt * 8 + i];
        const float m0 = __uint_as_float(pk << 16);
        const float m1 = __uint_as_float(pk & 0xffff0000u);
        const float sv0 = kt ? S1[2 * i]     : S0[2 * i];
        const float sv1 = kt ? S1[2 * i + 1] : S0[2 * i + 1];
        w32[kt * 16 + 2 * i]     = fmaf(sv0, SCALE, m0);
        w32[kt * 16 + 2 * i + 1] = fmaf(sv1, SCALE, m1);
      }
    float t16[16], t8[8], t4[4];
    #pragma unroll
    for (int i = 0; i < 16; ++i) t16[i] = fmaxf(w32[2 * i], w32[2 * i + 1]);
    #pragma unroll
    for (int i = 0; i < 8; ++i)  t8[i] = fmaxf(t16[2 * i], t16[2 * i + 1]);
    #pragma unroll
    for (int i = 0; i < 4; ++i)  t4[i] = fmaxf(t8[2 * i], t8[2 * i + 1]);
    float mx = fmaxf(fmaxf(t4[0], t4[1]), fmaxf(t4[2], t4[3]));
    mx = fmaxf(mx, __shfl_xor(mx, 32));
    #pragma unroll
    for (int i = 0; i < 32; ++i) w32[i] = __expf(w32[i] - mx);
    #pragma unroll
    for (int i = 0; i < 16; ++i) t16[i] = w32[2 * i] + w32[2 * i + 1];
    #pragma unroll
    for (int i = 0; i < 8; ++i)  t8[i] = t16[2 * i] + t16[2 * i + 1];
    #pragma unroll
    for (int i = 0; i < 4; ++i)  t4[i] = t8[2 * i] + t8[2 * i + 1];
    float sum = (t4[0] + t4[1]) + (t4[2] + t4[3]);
    sum += __shfl_xor(sum, 32);
    const float inv = 1.0f / sum;   // sum >= 1 always
    #pragma unroll
    for (int i = 0; i < 32; ++i) w32[i] *= inv;

    // ---- pack P to bf16 pairs + partner exchange -> PV A-fragments ----
    unsigned pw[16];
    #pragma unroll
    for (int i = 0; i < 16; ++i)
      pw[i] = cvt_pk_bf16(w32[2 * i], w32[2 * i + 1]);
    short8 pa[4];
    #pragma unroll
    for (int ks = 0; ks < 4; ++ks) {
      const unsigned q0 = pw[ks * 4 + 0], q1 = pw[ks * 4 + 1];
      const unsigned q2 = pw[ks * 4 + 2], q3 = pw[ks * 4 + 3];
      const unsigned t0 = hi ? q0 : q2;
      const unsigned t1 = hi ? q1 : q3;
      const unsigned x0 = __shfl_xor(t0, 32);
      const unsigned x1 = __shfl_xor(t1, 32);
      union { unsigned u[4]; short8 s; } u;
      u.u[0] = hi ? x0 : q0;
      u.u[1] = hi ? x1 : q1;
      u.u[2] = hi ? q2 : x0;
      u.u[3] = hi ? q3 : x1;
      pa[ks] = u.s;
    }

    // ---- PV: O[q][hd] = W @ V, K-dim = 64 keys = 4 steps of 16 ----
    float16v aO;
    #pragma unroll
    for (int i = 0; i < 16; ++i) aO[i] = 0.f;
    #pragma unroll
    for (int ks = 0; ks < 4; ++ks) {
      const short8 bv8 = *(const short8*)&sVt[cl * VP + ks * 16 + hi * 8];
      aO = MFMA32(pa[ks], bv8, aO);
    }

    // ---- O store into dead x region ----
    #pragma unroll
    for (int i = 0; i < 16; ++i) {
      const int tok = (i & 3) + 8 * (i >> 2) + 4 * hi + b * 32;
      if (tok < NTOK)
        sO[tok * XPITCH + h * 32 + cl] = (short)f2b(aO[i]);
    }
    BAR();   // (2) all scratch reads done before next pair overwrites
  }
  // Last BAR also makes all O rows visible for the output projection.

  // ---- output projection: each wave 96 cols; out = O @ Wp + bp ----
  // wb[0..11] already hold Wp tiles 0..11 (prefetched at p=5 tail).
  const unsigned short* const wp = g_wT + 442368 + wv * 36864 + lane * 8;

  float biasP[6];
  #pragma unroll
  for (int nt = 0; nt < 6; ++nt) {
    const int col = wv * 96 + nt * 16 + c;
    biasP[nt] = dt ? ((const float*)bpg_)[col] : b2f(((const unsigned short*)bpg_)[col]);
  }

  float4v aP[4][6];
  #pragma unroll
  for (int mt = 0; mt < 4; ++mt)
    #pragma unroll
    for (int nt = 0; nt < 6; ++nt) aP[mt][nt] = z4;

  short8 af[2][4];
  #pragma unroll
  for (int mt = 0; mt < 4; ++mt) {
    int row = mt * 16 + c; if (row > NTOK - 1) row = NTOK - 1;
    af[0][mt] = *(const short8*)&sO[row * XPITCH + qd * 8];
  }

  #pragma unroll
  for (int ks = 0; ks < 12; ++ks) {
    const int cs = ks & 1;
    if (ks < 11) {
      #pragma unroll
      for (int mt = 0; mt < 4; ++mt) {
        int row = mt * 16 + c; if (row > NTOK - 1) row = NTOK - 1;
        af[cs ^ 1][mt] = *(const short8*)&sO[row * XPITCH + (ks + 1) * 32 + qd * 8];
      }
    }
    const int s = cs * 6;
    #pragma unroll
    for (int nt = 0; nt < 6; ++nt) {
      aP[0][nt] = MFMA16(af[cs][0], wb[s + nt], aP[0][nt]);
      aP[1][nt] = MFMA16(af[cs][1], wb[s + nt], aP[1][nt]);
      aP[2][nt] = MFMA16(af[cs][2], wb[s + nt], aP[2][nt]);
      aP[3][nt] = MFMA16(af[cs][3], wb[s + nt], aP[3][nt]);
      if (ks < 10) wb[s + nt] = *(const short8*)(wp + ((ks + 2) * 6 + nt) * 512);
    }
  }

  #pragma unroll
  for (int nt = 0; nt < 6; ++nt) {
    const int col = wv * 96 + nt * 16 + c;
    #pragma unroll
    for (int mt = 0; mt < 4; ++mt) {
      #pragma unroll
      for (int r = 0; r < 4; ++r) {
        const int m = mt * 16 + qd * 4 + r;
        if (m < NTOK) {
          const float v = aP[mt][nt][r] + biasP[nt];
          const size_t off = (size_t)win * (NTOK * DMODEL) + m * DMODEL + col;
          if (dt) ((float*)outg_)[off] = v;
          else    ((unsigned short*)outg_)[off] = f2b(v);
        }
      }
    }
  }
}

extern "C" void kernel_launch(void* const* d_in, const int* in_sizes, int n_in,
                              void* d_out, int out_size, void* d_ws, size_t ws_size,
                              hipStream_t stream) {
  const void* x    = d_in[0];
  const void* mask = d_in[1];
  const void* Wq   = d_in[2];
  const void* bq   = d_in[3];
  const void* Wk   = d_in[4];
  const void* bk   = d_in[5];
  const void* Wv   = d_in[6];
  const void* bv   = d_in[7];
  const void* Wp   = d_in[8];
  const void* bp   = d_in[9];

  detect_dtype<<<1, 256, 0, stream>>>((const unsigned short*)x);
  prep_weights<<<(4 * DMODEL * DMODEL) / 256, 256, 0, stream>>>(Wq, Wk, Wv, Wp);
  win_attn<<<NWIN, 256, 0, stream>>>(x, mask, bq, bk, bv, bp, d_out);
}